// Round 3
// baseline (1236.535 us; speedup 1.0000x reference)
//
#include <hip/hip_runtime.h>
#include <cstdint>

// Problem constants
#define E_ 8
#define D_ 1024
#define H_ 4096
#define NTOK 16384   // B*S = 4*4096

typedef unsigned short ushort_t;
typedef __attribute__((ext_vector_type(8))) short short8;
typedef __attribute__((ext_vector_type(4))) float f32x4;

__device__ __forceinline__ ushort_t f2bf(float f) {
  uint32_t u = __builtin_bit_cast(uint32_t, f);
  uint32_t r = (u + 0x7fffu + ((u >> 16) & 1u)) >> 16;  // RNE
  return (ushort_t)r;
}

__device__ __forceinline__ void gload_lds16(const void* g, void* l) {
  __builtin_amdgcn_global_load_lds(
      (const __attribute__((address_space(1))) uint32_t*)g,
      (__attribute__((address_space(3))) uint32_t*)l, 16, 0, 0);
}

// ---------------- init: zero counts/cursor + rawbase ----------------
__global__ void init_kernel(int* counts_cursor, float* rawbase) {
  int tid = threadIdx.x + blockIdx.x * 256;
  if (tid < 16) counts_cursor[tid] = 0;
  if (tid < E_ * D_) rawbase[tid] = 0.f;   // grid 32*256 = 8192 threads
}

// ---------------- transpose fp32 [E][R][C] -> bf16 [E][C][R] ----------------
__global__ void transpose_bf16(const float* __restrict__ in, ushort_t* __restrict__ out,
                               int R, int C) {
  __shared__ float t[32][33];
  const int e = blockIdx.z;
  const float* ip = in + (size_t)e * R * C;
  ushort_t* op = out + (size_t)e * R * C;
  const int c0 = blockIdx.x * 32, r0 = blockIdx.y * 32;
  const int tx = threadIdx.x, ty = threadIdx.y;
#pragma unroll
  for (int q = 0; q < 4; ++q)
    t[ty + q * 8][tx] = ip[(size_t)(r0 + ty + q * 8) * C + c0 + tx];
  __syncthreads();
#pragma unroll
  for (int q = 0; q < 4; ++q) {
    int c = c0 + ty + q * 8;
    op[(size_t)c * R + r0 + tx] = f2bf(t[tx][ty + q * 8]);
  }
}

// ---------------- per-expert base vector: rawbase[e][d] = sum_h relu(b1[e][h]) * W2[e][h][d] ----------------
__global__ void base_kernel(const float* __restrict__ b1, const float* __restrict__ W2,
                            float* __restrict__ rawbase) {
  const int e = blockIdx.y;
  const int d = blockIdx.x * 256 + threadIdx.x;
  const int h0 = blockIdx.z * 512;
  const float* w = W2 + (size_t)e * H_ * D_ + (size_t)h0 * D_ + d;
  const float* b = b1 + e * H_ + h0;
  float s = 0.f;
#pragma unroll 4
  for (int h = 0; h < 512; ++h) {
    float hv = fmaxf(b[h], 0.f);
    s += hv * w[(size_t)h * D_];
  }
  atomicAdd(&rawbase[e * D_ + d], s);
}

// adj[e][d] = sum_i (rawbase[i][d] + b2[i][d]) - rawbase[e][d]
__global__ void adj_kernel(const float* __restrict__ rawbase, const float* __restrict__ b2,
                           float* __restrict__ adj) {
  int i = blockIdx.x * 256 + threadIdx.x;  // 8192
  int d = i & (D_ - 1);
  int e = i >> 10;
  float tot = 0.f;
#pragma unroll
  for (int ii = 0; ii < E_; ++ii) tot += rawbase[ii * D_ + d] + b2[ii * D_ + d];
  adj[i] = tot - rawbase[e * D_ + d];
}

// ---------------- router: fp32 logits -> argmax (first-max tiebreak), count per expert ----------------
__global__ void router_kernel(const float* __restrict__ x, const float* __restrict__ Wr,
                              const float* __restrict__ br, int* __restrict__ idx,
                              int* __restrict__ counts) {
  __shared__ float wr_s[E_][D_];   // transposed Wr: wr_s[e][d]
  const int tid = threadIdx.x;
  for (int j = tid; j < E_ * D_; j += 256) {
    int e = j & 7, d = j >> 3;
    wr_s[e][d] = Wr[j];
  }
  __syncthreads();
  const int wid = tid >> 6, l = tid & 63;
  const int t0 = blockIdx.x * 32 + wid * 8;
  for (int tt = 0; tt < 8; ++tt) {
    int t = t0 + tt;
    const float* xr = x + (size_t)t * D_;
    float s[E_];
#pragma unroll
    for (int e = 0; e < E_; ++e) s[e] = 0.f;
    for (int q = 0; q < D_ / 64; ++q) {
      float xv = xr[q * 64 + l];
#pragma unroll
      for (int e = 0; e < E_; ++e) s[e] += xv * wr_s[e][q * 64 + l];
    }
#pragma unroll
    for (int e = 0; e < E_; ++e) {
#pragma unroll
      for (int off = 32; off > 0; off >>= 1) s[e] += __shfl_xor(s[e], off, 64);
    }
    if (l == 0) {
      float best = s[0] + br[0];
      int bi = 0;
#pragma unroll
      for (int e = 1; e < E_; ++e) {
        float v = s[e] + br[e];
        if (v > best) { best = v; bi = e; }   // strict >: first-max like argmax
      }
      idx[t] = bi;
      atomicAdd(&counts[bi], 1);
    }
  }
}

// ---------------- scan + build compact tile worklists ----------------
// item = (e<<16) | (tm<<8) | tn.  meta: [0]=n1 [1]=n2 [2]=ctr1 [3]=ctr2
__global__ void scan_build(const int* __restrict__ counts, int* __restrict__ offsets,
                           int* __restrict__ work1, int* __restrict__ work2,
                           int* __restrict__ meta) {
  if (threadIdx.x != 0 || blockIdx.x != 0) return;
  int acc = 0;
  int cnt[E_];
  for (int e = 0; e < E_; ++e) {
    cnt[e] = counts[e];
    offsets[e] = acc;
    acc += cnt[e];
  }
  offsets[E_] = acc;
  int n1 = 0, n2 = 0;
  for (int e = 0; e < E_; ++e) {
    int nt = (cnt[e] + 255) >> 8;
    for (int tn = 0; tn < H_ / 256; ++tn)
      for (int tm = 0; tm < nt; ++tm)
        work1[n1++] = (e << 16) | (tm << 8) | tn;
    for (int tn = 0; tn < D_ / 256; ++tn)
      for (int tm = 0; tm < nt; ++tm)
        work2[n2++] = (e << 16) | (tm << 8) | tn;
  }
  meta[0] = n1;
  meta[1] = n2;
  meta[2] = 0;
  meta[3] = 0;
}

// ---------------- scatter: counting-sort tokens, gather x -> bf16 xg ----------------
__global__ void scatter_kernel(const float* __restrict__ x, const int* __restrict__ idx,
                               const int* __restrict__ offsets, int* __restrict__ cursor,
                               int* __restrict__ perm, ushort_t* __restrict__ xg) {
  const int tid = threadIdx.x;
  const int wid = tid >> 6, l = tid & 63;
  const int t = blockIdx.x * 4 + wid;
  int e = idx[t];
  int slot = 0;
  if (l == 0) {
    slot = offsets[e] + atomicAdd(&cursor[e], 1);
    perm[slot] = t;
  }
  slot = __shfl(slot, 0, 64);
  const float4* xr = (const float4*)(x + (size_t)t * D_);
  ushort_t* xo = xg + (size_t)slot * D_;
#pragma unroll
  for (int q = 0; q < 4; ++q) {
    float4 v = xr[q * 64 + l];
    ushort4 o;
    o.x = f2bf(v.x); o.y = f2bf(v.y); o.z = f2bf(v.z); o.w = f2bf(v.w);
    *(ushort4*)(xo + (size_t)(q * 64 + l) * 4) = o;
  }
}

// ---------------- persistent grouped GEMM: 256x256 tile, BK=64, 8-phase, work-queue ----------------
// 512 threads = 8 waves (2 M x 4 N). LDS: 2 bufs x {A0,A1,B0,B1} halves of [128][64] bf16.
// XOR swizzle on 16B units (pre-swizzled global source; linear global_load_lds dest).
// Phase order (mh,nh)=(0,0),(0,1),(1,1),(1,0): A frags reused across pairs, bq0 live ph1->ph4
// => 24 ds_read_b128/K-tile/wave (optimal). Counted vmcnt(4) at ph4/ph8 only. setprio around MFMA.
// MODE 1: hb = relu(xg @ W1t^T + b1) (bf16) ; MODE 2: out[perm] = hb @ W2t^T + adj (f32)

__device__ __forceinline__ void stage_half(const ushort_t* __restrict__ gbase, int rstride,
                                           int row0, int rowmax, int kcol,
                                           ushort_t* ldsb, int wid, int l) {
#pragma unroll
  for (int r = 0; r < 2; ++r) {
    int idx = r * 512 + wid * 64 + l;
    int lrow = idx >> 3;
    int u = idx & 7;
    int grow = row0 + lrow;
    if (grow > rowmax) grow = rowmax;
    const ushort_t* src = gbase + (size_t)grow * rstride + kcol + ((u ^ (lrow & 7)) << 3);
    gload_lds16(src, ldsb + ((r * 512 + wid * 64) << 3));
  }
}

#define RD_AF(bufc, mh)                                                                 \
  _Pragma("unroll") for (int i_ = 0; i_ < 4; ++i_) {                                    \
    const ushort_t* p_ = &lds[bufc][mh][(wm * 64 + i_ * 16 + lr) * 64];                 \
    _Pragma("unroll") for (int ks_ = 0; ks_ < 2; ++ks_)                                 \
      af[i_][ks_] = *(const short8*)&p_[(((ks_ * 4 + lh) ^ lx) << 3)];                  \
  }

#define RD_BQ(bufc, nh, dst)                                                            \
  _Pragma("unroll") for (int j_ = 0; j_ < 2; ++j_) {                                    \
    const ushort_t* p_ = &lds[bufc][2 + (nh)][(wn * 32 + j_ * 16 + lr) * 64];           \
    _Pragma("unroll") for (int ks_ = 0; ks_ < 2; ++ks_)                                 \
      dst[j_][ks_] = *(const short8*)&p_[(((ks_ * 4 + lh) ^ lx) << 3)];                 \
  }

#define MM(mb, jb, bq)                                                                  \
  _Pragma("unroll") for (int ks_ = 0; ks_ < 2; ++ks_)                                   \
    _Pragma("unroll") for (int i_ = 0; i_ < 4; ++i_)                                    \
      _Pragma("unroll") for (int j_ = 0; j_ < 2; ++j_)                                  \
        acc[(mb) + i_][(jb) + j_] = __builtin_amdgcn_mfma_f32_16x16x32_bf16(            \
            af[i_][ks_], bq[j_][ks_], acc[(mb) + i_][(jb) + j_], 0, 0, 0);

#define PHASE(VM, RDS, MMS, ...)                                                        \
  {                                                                                     \
    RDS                                                                                 \
    __VA_ARGS__;                                                                        \
    __builtin_amdgcn_s_barrier();                                                       \
    asm volatile("s_waitcnt lgkmcnt(0)" ::: "memory");                                  \
    __builtin_amdgcn_sched_barrier(0);                                                  \
    __builtin_amdgcn_s_setprio(1);                                                      \
    MMS                                                                                 \
    __builtin_amdgcn_s_setprio(0);                                                      \
    if (VM) asm volatile("s_waitcnt vmcnt(4)" ::: "memory");                            \
    __builtin_amdgcn_s_barrier();                                                       \
  }

template <int MODE>
__global__ __launch_bounds__(512, 2) void ffn_gemm(
    const ushort_t* __restrict__ A_all, const ushort_t* __restrict__ Bw,
    const float* __restrict__ bias, const int* __restrict__ offs,
    const int* __restrict__ perm, float* __restrict__ out, ushort_t* __restrict__ hbo,
    const int* __restrict__ work, const int* __restrict__ nw_p, int* __restrict__ ctr) {
  constexpr int Kd = (MODE == 1) ? D_ : H_;
  constexpr int Nd = (MODE == 1) ? H_ : D_;
  constexpr int NKT = Kd / 64;

  __shared__ __align__(16) ushort_t lds[2][4][128 * 64];  // 128 KiB
  __shared__ int s_item;

  const int tid = threadIdx.x;
  const int wid = tid >> 6, l = tid & 63;
  const int wm = wid >> 2, wn = wid & 3;
  const int lr = l & 15, lh = l >> 4, lx = l & 7;
  const int nw = *nw_p;

  for (;;) {
    if (tid == 0) s_item = atomicAdd(ctr, 1);
    __syncthreads();   // broadcasts s_item; full waitcnt drain protects LDS reuse
    const int wi = s_item;
    if (wi >= nw) return;
    const int item = work[wi];
    const int e = item >> 16, tm = (item >> 8) & 255, tn = item & 255;
    const int ms = offs[e];
    const int M = offs[e + 1] - ms;

    const ushort_t* Ab = A_all + (size_t)ms * Kd;
    const ushort_t* Bb = Bw + (size_t)e * ((size_t)Nd * Kd);
    const int rowmaxA = M - 1;
    const int arow0 = tm * 256;
    const int brow0 = tn * 256;

    f32x4 acc[8][4];
#pragma unroll
    for (int i = 0; i < 8; ++i)
#pragma unroll
      for (int j = 0; j < 4; ++j) acc[i][j] = (f32x4){0.f, 0.f, 0.f, 0.f};
    short8 af[4][2], bq0[2][2], bq1[2][2];

    // prologue: buf0 <- tile0 (A0,B0,A1,B1), buf1 <- tile1 (A0,B0)
    stage_half(Ab, Kd, arow0 + 0,   rowmaxA, 0,  &lds[0][0][0], wid, l);
    stage_half(Bb, Kd, brow0 + 0,   Nd - 1,  0,  &lds[0][2][0], wid, l);
    stage_half(Ab, Kd, arow0 + 128, rowmaxA, 0,  &lds[0][1][0], wid, l);
    stage_half(Bb, Kd, brow0 + 128, Nd - 1,  0,  &lds[0][3][0], wid, l);
    stage_half(Ab, Kd, arow0 + 0,   rowmaxA, 64, &lds[1][0][0], wid, l);
    stage_half(Bb, Kd, brow0 + 0,   Nd - 1,  64, &lds[1][2][0], wid, l);
    asm volatile("s_waitcnt vmcnt(4)" ::: "memory");
    __builtin_amdgcn_s_barrier();

    for (int it = 0; it < NKT / 2; ++it) {
      const int k1 = (2 * it + 1) * 64;
      int t2 = 2 * it + 2; if (t2 > NKT - 1) t2 = NKT - 1;
      int t3 = 2 * it + 3; if (t3 > NKT - 1) t3 = NKT - 1;
      const int k2 = t2 * 64, k3 = t3 * 64;
      // buf0 compute (K-tile 2it)
      PHASE(0, RD_AF(0, 0) RD_BQ(0, 0, bq0), MM(0, 0, bq0),
            stage_half(Ab, Kd, arow0 + 128, rowmaxA, k1, &lds[1][1][0], wid, l))
      PHASE(0, RD_BQ(0, 1, bq1),             MM(0, 2, bq1),
            stage_half(Bb, Kd, brow0 + 128, Nd - 1,  k1, &lds[1][3][0], wid, l))
      PHASE(0, RD_AF(0, 1),                  MM(4, 2, bq1),
            stage_half(Bb, Kd, brow0 + 0,   Nd - 1,  k2, &lds[0][2][0], wid, l))
      PHASE(1, ,                             MM(4, 0, bq0),
            stage_half(Ab, Kd, arow0 + 0,   rowmaxA, k2, &lds[0][0][0], wid, l))
      // buf1 compute (K-tile 2it+1)
      PHASE(0, RD_AF(1, 0) RD_BQ(1, 0, bq0), MM(0, 0, bq0),
            stage_half(Ab, Kd, arow0 + 128, rowmaxA, k2, &lds[0][1][0], wid, l))
      PHASE(0, RD_BQ(1, 1, bq1),             MM(0, 2, bq1),
            stage_half(Bb, Kd, brow0 + 128, Nd - 1,  k2, &lds[0][3][0], wid, l))
      PHASE(0, RD_AF(1, 1),                  MM(4, 2, bq1),
            stage_half(Bb, Kd, brow0 + 0,   Nd - 1,  k3, &lds[1][2][0], wid, l))
      PHASE(1, ,                             MM(4, 0, bq0),
            stage_half(Ab, Kd, arow0 + 0,   rowmaxA, k3, &lds[1][0][0], wid, l))
    }

    // epilogue: C[row = tm*256 + mh*128 + wm*64 + i*16 + lh*4 + rr]
    //            [col = tn*256 + nh*128 + wn*32 + j*16 + lr]
    float bv[4];
#pragma unroll
    for (int n = 0; n < 4; ++n)
      bv[n] = bias[e * Nd + tn * 256 + (n >> 1) * 128 + wn * 32 + (n & 1) * 16 + lr];
#pragma unroll
    for (int m = 0; m < 8; ++m) {
      const int mh = m >> 2, i = m & 3;
#pragma unroll
      for (int rr = 0; rr < 4; ++rr) {
        int grow = tm * 256 + mh * 128 + wm * 64 + i * 16 + lh * 4 + rr;
        if (grow < M) {
          if (MODE == 1) {
            size_t rowoff = (size_t)(ms + grow) * H_;
#pragma unroll
            for (int n = 0; n < 4; ++n) {
              float v = acc[m][n][rr] + bv[n];
              v = fmaxf(v, 0.f);
              hbo[rowoff + tn * 256 + (n >> 1) * 128 + wn * 32 + (n & 1) * 16 + lr] = f2bf(v);
            }
          } else {
            int tok = perm[ms + grow];
            size_t rowoff = (size_t)tok * D_;
#pragma unroll
            for (int n = 0; n < 4; ++n)
              out[rowoff + tn * 256 + (n >> 1) * 128 + wn * 32 + (n & 1) * 16 + lr] =
                  acc[m][n][rr] + bv[n];
          }
        }
      }
    }
  }
}

extern "C" void kernel_launch(void* const* d_in, const int* in_sizes, int n_in,
                              void* d_out, int out_size, void* d_ws, size_t ws_size,
                              hipStream_t stream) {
  const float* x  = (const float*)d_in[0];
  const float* W1 = (const float*)d_in[1];
  const float* b1 = (const float*)d_in[2];
  const float* W2 = (const float*)d_in[3];
  const float* b2 = (const float*)d_in[4];
  const float* Wr = (const float*)d_in[5];
  const float* br = (const float*)d_in[6];
  float* out = (float*)d_out;

  // workspace layout (needs ~302.3 MB)
  char* ws = (char*)d_ws;
  ushort_t* W1t   = (ushort_t*)(ws);                    // [E][H][D] bf16: 67108864 B
  ushort_t* W2t   = (ushort_t*)(ws + 67108864);         // [E][D][H] bf16: 67108864 B
  ushort_t* xg    = (ushort_t*)(ws + 134217728);        // [N][D]   bf16: 33554432 B
  ushort_t* hb    = (ushort_t*)(ws + 167772160);        // [N][H]   bf16: 134217728 B
  float*    rawbase = (float*)(ws + 301989888);         // [E][D] f32
  float*    adj   = (float*)(ws + 302022656);           // [E][D] f32
  int*      idx   = (int*)(ws + 302055424);             // [N]
  int*      perm  = (int*)(ws + 302120960);             // [N]
  int*      counts = (int*)(ws + 302186496);            // 8 + 8 cursor
  int*      cursor = counts + 8;
  int*      offsets = (int*)(ws + 302186624);           // 9 ints
  int*      meta   = (int*)(ws + 302186752);            // [n1, n2, ctr1, ctr2]
  int*      work1  = (int*)(ws + 302186880);            // <=2048 ints
  int*      work2  = (int*)(ws + 302195072);            // <=2048 ints

  init_kernel<<<32, 256, 0, stream>>>(counts, rawbase);
  transpose_bf16<<<dim3(H_ / 32, D_ / 32, E_), dim3(32, 8), 0, stream>>>(W1, W1t, D_, H_);
  transpose_bf16<<<dim3(D_ / 32, H_ / 32, E_), dim3(32, 8), 0, stream>>>(W2, W2t, H_, D_);
  base_kernel<<<dim3(4, E_, 8), 256, 0, stream>>>(b1, W2, rawbase);
  adj_kernel<<<32, 256, 0, stream>>>(rawbase, b2, adj);
  router_kernel<<<512, 256, 0, stream>>>(x, Wr, br, idx, counts);
  scan_build<<<1, 64, 0, stream>>>(counts, offsets, work1, work2, meta);
  scatter_kernel<<<NTOK / 4, 256, 0, stream>>>(x, idx, offsets, cursor, perm, xg);
  ffn_gemm<1><<<256, 512, 0, stream>>>(xg, W1t, b1, offsets, nullptr, nullptr, hb,
                                       work1, meta + 0, meta + 2);
  ffn_gemm<2><<<256, 512, 0, stream>>>(hb, W2t, adj, offsets, perm, out, nullptr,
                                       work2, meta + 1, meta + 3);
}

// Round 4
// 959.777 us; speedup vs baseline: 1.2884x; 1.2884x over previous
//
#include <hip/hip_runtime.h>
#include <cstdint>

// Problem constants
#define E_ 8
#define D_ 1024
#define H_ 4096
#define NTOK 16384   // B*S = 4*4096

typedef unsigned short ushort_t;
typedef __attribute__((ext_vector_type(8))) short short8;
typedef __attribute__((ext_vector_type(4))) float f32x4;

__device__ __forceinline__ ushort_t f2bf(float f) {
  uint32_t u = __builtin_bit_cast(uint32_t, f);
  uint32_t r = (u + 0x7fffu + ((u >> 16) & 1u)) >> 16;  // RNE
  return (ushort_t)r;
}

__device__ __forceinline__ void gload_lds16(const void* g, void* l) {
  __builtin_amdgcn_global_load_lds(
      (const __attribute__((address_space(1))) uint32_t*)g,
      (__attribute__((address_space(3))) uint32_t*)l, 16, 0, 0);
}

// ---------------- init: zero counts/cursor + rawbase ----------------
__global__ void init_kernel(int* counts_cursor, float* rawbase) {
  int tid = threadIdx.x + blockIdx.x * 256;
  if (tid < 16) counts_cursor[tid] = 0;
  if (tid < E_ * D_) rawbase[tid] = 0.f;   // grid 32*256 = 8192 threads
}

// ---------------- transpose fp32 [E][R][C] -> bf16 [E][C][R], 64x64 tiles ----------------
__global__ void transpose_bf16(const float* __restrict__ in, ushort_t* __restrict__ out,
                               int R, int C) {
  __shared__ float t[64][65];
  const int e = blockIdx.z;
  const float* ip = in + (size_t)e * R * C;
  ushort_t* op = out + (size_t)e * R * C;
  const int c0 = blockIdx.x * 64, r0 = blockIdx.y * 64;
  const int tid = threadIdx.x;
  const int rlane = tid >> 6;      // 0..3 (uniform per wave)
  const int cl64 = tid & 63;
#pragma unroll
  for (int q = 0; q < 16; ++q) {
    int rl = q * 4 + rlane;
    t[rl][cl64] = ip[(size_t)(r0 + rl) * C + c0 + cl64];
  }
  __syncthreads();
  const int csub = tid >> 5;       // 0..7
  const int rp = (tid & 31) * 2;   // 0,2,..,62
#pragma unroll
  for (int w = 0; w < 8; ++w) {
    int cl = w * 8 + csub;
    ushort2 v;
    v.x = f2bf(t[rp][cl]);
    v.y = f2bf(t[rp + 1][cl]);
    *(ushort2*)&op[(size_t)(c0 + cl) * R + r0 + rp] = v;
  }
}

// ---------------- per-expert base vector: rawbase[e][d] = sum_h relu(b1[e][h]) * W2[e][h][d] ----------------
__global__ void base_kernel(const float* __restrict__ b1, const float* __restrict__ W2,
                            float* __restrict__ rawbase) {
  const int e = blockIdx.y;
  const int d = blockIdx.x * 256 + threadIdx.x;
  const int h0 = blockIdx.z * 512;
  const float* w = W2 + (size_t)e * H_ * D_ + (size_t)h0 * D_ + d;
  const float* b = b1 + e * H_ + h0;
  float s = 0.f;
#pragma unroll 4
  for (int h = 0; h < 512; ++h) {
    float hv = fmaxf(b[h], 0.f);
    s += hv * w[(size_t)h * D_];
  }
  atomicAdd(&rawbase[e * D_ + d], s);
}

// adj[e][d] = sum_i (rawbase[i][d] + b2[i][d]) - rawbase[e][d]
__global__ void adj_kernel(const float* __restrict__ rawbase, const float* __restrict__ b2,
                           float* __restrict__ adj) {
  int i = blockIdx.x * 256 + threadIdx.x;  // 8192
  int d = i & (D_ - 1);
  int e = i >> 10;
  float tot = 0.f;
#pragma unroll
  for (int ii = 0; ii < E_; ++ii) tot += rawbase[ii * D_ + d] + b2[ii * D_ + d];
  adj[i] = tot - rawbase[e * D_ + d];
}

// ---------------- router: fp32 logits -> argmax (first-max tiebreak), count per expert ----------------
__global__ void router_kernel(const float* __restrict__ x, const float* __restrict__ Wr,
                              const float* __restrict__ br, int* __restrict__ idx,
                              int* __restrict__ counts) {
  __shared__ float wr_s[E_][D_];   // transposed Wr: wr_s[e][d]
  const int tid = threadIdx.x;
  for (int j = tid; j < E_ * D_; j += 256) {
    int e = j & 7, d = j >> 3;
    wr_s[e][d] = Wr[j];
  }
  __syncthreads();
  const int wid = tid >> 6, l = tid & 63;
  const int t0 = blockIdx.x * 32 + wid * 8;
  for (int tt = 0; tt < 8; ++tt) {
    int t = t0 + tt;
    const float* xr = x + (size_t)t * D_;
    float s[E_];
#pragma unroll
    for (int e = 0; e < E_; ++e) s[e] = 0.f;
    for (int q = 0; q < D_ / 64; ++q) {
      float xv = xr[q * 64 + l];
#pragma unroll
      for (int e = 0; e < E_; ++e) s[e] += xv * wr_s[e][q * 64 + l];
    }
#pragma unroll
    for (int e = 0; e < E_; ++e) {
#pragma unroll
      for (int off = 32; off > 0; off >>= 1) s[e] += __shfl_xor(s[e], off, 64);
    }
    if (l == 0) {
      float best = s[0] + br[0];
      int bi = 0;
#pragma unroll
      for (int e = 1; e < E_; ++e) {
        float v = s[e] + br[e];
        if (v > best) { best = v; bi = e; }   // strict >: first-max like argmax
      }
      idx[t] = bi;
      atomicAdd(&counts[bi], 1);
    }
  }
}

// ---------------- scan + build compact tile worklists ----------------
// item = (e<<16) | (tm<<8) | tn.  meta: [0]=n1 [1]=n2
__global__ void scan_build(const int* __restrict__ counts, int* __restrict__ offsets,
                           int* __restrict__ work1, int* __restrict__ work2,
                           int* __restrict__ meta) {
  if (threadIdx.x != 0 || blockIdx.x != 0) return;
  int acc = 0;
  int cnt[E_];
  for (int e = 0; e < E_; ++e) {
    cnt[e] = counts[e];
    offsets[e] = acc;
    acc += cnt[e];
  }
  offsets[E_] = acc;
  int n1 = 0, n2 = 0;
  for (int e = 0; e < E_; ++e) {
    int nt = (cnt[e] + 255) >> 8;
    for (int tn = 0; tn < H_ / 256; ++tn)
      for (int tm = 0; tm < nt; ++tm)
        work1[n1++] = (e << 16) | (tm << 8) | tn;
    for (int tn = 0; tn < D_ / 256; ++tn)
      for (int tm = 0; tm < nt; ++tm)
        work2[n2++] = (e << 16) | (tm << 8) | tn;
  }
  meta[0] = n1;
  meta[1] = n2;
}

// ---------------- scatter: counting-sort tokens, gather x -> bf16 xg ----------------
__global__ void scatter_kernel(const float* __restrict__ x, const int* __restrict__ idx,
                               const int* __restrict__ offsets, int* __restrict__ cursor,
                               int* __restrict__ perm, ushort_t* __restrict__ xg) {
  const int tid = threadIdx.x;
  const int wid = tid >> 6, l = tid & 63;
  const int t = blockIdx.x * 4 + wid;
  int e = idx[t];
  int slot = 0;
  if (l == 0) {
    slot = offsets[e] + atomicAdd(&cursor[e], 1);
    perm[slot] = t;
  }
  slot = __shfl(slot, 0, 64);
  const float4* xr = (const float4*)(x + (size_t)t * D_);
  ushort_t* xo = xg + (size_t)slot * D_;
#pragma unroll
  for (int q = 0; q < 4; ++q) {
    float4 v = xr[q * 64 + l];
    ushort4 o;
    o.x = f2bf(v.x); o.y = f2bf(v.y); o.z = f2bf(v.z); o.w = f2bf(v.w);
    *(ushort4*)(xo + (size_t)(q * 64 + l) * 4) = o;
  }
}

// ---------------- grouped GEMM: 256x256 tile, BK=64, minimum-2-phase double buffer ----------------
// 512 threads = 8 waves (2 M x 4 N), per-wave output 128x64. LDS: 2 bufs x {A,B} of [256][64] bf16
// (128 KiB). XOR swizzle on 16B units: LDS[row][u] holds global unit u^(row&7) via pre-swizzled
// global source (linear global_load_lds dest); ds_read applies the same XOR -> 0 bank conflicts.
// Schedule per K-step: STAGE(next buf) FIRST, then 24x ds_read_b128 + 64 MFMA on cur buf, then
// one __syncthreads() (drains own vmcnt -> next buf ready). One tile per block (compact worklist).
// MODE 1: hb = relu(xg @ W1t^T + b1) (bf16) ; MODE 2: out[perm] = hb @ W2t^T + adj (f32)

template <int MODE>
__global__ __launch_bounds__(512, 2) void ffn_gemm(
    const ushort_t* __restrict__ A_all, const ushort_t* __restrict__ Bw,
    const float* __restrict__ bias, const int* __restrict__ offs,
    const int* __restrict__ perm, float* __restrict__ out, ushort_t* __restrict__ hbo,
    const int* __restrict__ work, const int* __restrict__ nw_p) {
  constexpr int Kd = (MODE == 1) ? D_ : H_;
  constexpr int Nd = (MODE == 1) ? H_ : D_;
  constexpr int NKT = Kd / 64;

  const int n1 = *nw_p;
  int bid = blockIdx.x;
  if (bid >= n1) return;
  {  // m204 bijective XCD swizzle over the worklist
    int q = n1 >> 3, r = n1 & 7;
    int xcd = bid & 7, pos = bid >> 3;
    bid = (xcd < r ? xcd * (q + 1) : r * (q + 1) + (xcd - r) * q) + pos;
  }
  const int item = work[bid];
  const int e = item >> 16, tm = (item >> 8) & 255, tn = item & 255;
  const int ms = offs[e];
  const int M = offs[e + 1] - ms;

  __shared__ __align__(16) ushort_t lds[2][2][256 * 64];  // 128 KiB

  const int tid = threadIdx.x;
  const int wid = tid >> 6, l = tid & 63;
  const int wm = wid >> 2, wn = wid & 3;
  const int lr = l & 15, lh = l >> 4, lx = l & 7;

  const ushort_t* Ab = A_all + (size_t)ms * Kd;
  const ushort_t* Bb = Bw + (size_t)e * ((size_t)Nd * Kd);
  const int arow0 = tm * 256;
  const int brow0 = tn * 256;
  const int rowmaxA = M - 1;

  // per-thread staging offsets (elements), pre-swizzled source unit
  int aoff[4], boff[4];
#pragma unroll
  for (int c = 0; c < 4; ++c) {
    int idx = c * 512 + tid;
    int lrow = idx >> 3;
    int u = (idx & 7) ^ (lrow & 7);
    int ga = arow0 + lrow;
    if (ga > rowmaxA) ga = rowmaxA;
    aoff[c] = ga * Kd + u * 8;
    boff[c] = (brow0 + lrow) * Kd + u * 8;
  }

#define STAGE(buf, kt)                                                                   \
  _Pragma("unroll") for (int c_ = 0; c_ < 4; ++c_) {                                     \
    gload_lds16(Ab + aoff[c_] + (kt) * 64, &lds[buf][0][(c_ * 512 + wid * 64) * 8]);     \
    gload_lds16(Bb + boff[c_] + (kt) * 64, &lds[buf][1][(c_ * 512 + wid * 64) * 8]);     \
  }

  f32x4 acc[8][4];
#pragma unroll
  for (int i = 0; i < 8; ++i)
#pragma unroll
    for (int j = 0; j < 4; ++j) acc[i][j] = (f32x4){0.f, 0.f, 0.f, 0.f};

  STAGE(0, 0)
  __syncthreads();

  for (int kt = 0; kt < NKT; ++kt) {
    const int cur = kt & 1;
    if (kt + 1 < NKT) { STAGE(cur ^ 1, kt + 1) }
    const ushort_t* la = &lds[cur][0][0];
    const ushort_t* lb = &lds[cur][1][0];
#pragma unroll
    for (int ks = 0; ks < 2; ++ks) {
      short8 af[8], bq[4];
      const int uo = (((ks * 4 + lh) ^ lx) << 3);
#pragma unroll
      for (int i = 0; i < 8; ++i)
        af[i] = *(const short8*)&la[(wm * 128 + i * 16 + lr) * 64 + uo];
#pragma unroll
      for (int j = 0; j < 4; ++j)
        bq[j] = *(const short8*)&lb[(wn * 64 + j * 16 + lr) * 64 + uo];
#pragma unroll
      for (int i = 0; i < 8; ++i)
#pragma unroll
        for (int j = 0; j < 4; ++j)
          acc[i][j] = __builtin_amdgcn_mfma_f32_16x16x32_bf16(af[i], bq[j], acc[i][j], 0, 0, 0);
    }
    __syncthreads();   // drains own vmcnt(0)+lgkm: next buf fully staged for all waves
  }

  // epilogue: C[row = tm*256 + wm*128 + i*16 + lh*4 + rr][col = tn*256 + wn*64 + j*16 + lr]
  const int gcolbase = tn * 256 + wn * 64 + lr;
  float bv[4];
#pragma unroll
  for (int j = 0; j < 4; ++j) bv[j] = bias[e * Nd + gcolbase + j * 16];
#pragma unroll
  for (int i = 0; i < 8; ++i) {
#pragma unroll
    for (int rr = 0; rr < 4; ++rr) {
      int grow = tm * 256 + wm * 128 + i * 16 + lh * 4 + rr;
      if (grow < M) {
        if (MODE == 1) {
          size_t rowoff = (size_t)(ms + grow) * H_;
#pragma unroll
          for (int j = 0; j < 4; ++j) {
            float v = acc[i][j][rr] + bv[j];
            v = fmaxf(v, 0.f);
            hbo[rowoff + gcolbase + j * 16] = f2bf(v);
          }
        } else {
          int tok = perm[ms + grow];
          size_t rowoff = (size_t)tok * D_;
#pragma unroll
          for (int j = 0; j < 4; ++j)
            out[rowoff + gcolbase + j * 16] = acc[i][j][rr] + bv[j];
        }
      }
    }
  }
#undef STAGE
}

extern "C" void kernel_launch(void* const* d_in, const int* in_sizes, int n_in,
                              void* d_out, int out_size, void* d_ws, size_t ws_size,
                              hipStream_t stream) {
  const float* x  = (const float*)d_in[0];
  const float* W1 = (const float*)d_in[1];
  const float* b1 = (const float*)d_in[2];
  const float* W2 = (const float*)d_in[3];
  const float* b2 = (const float*)d_in[4];
  const float* Wr = (const float*)d_in[5];
  const float* br = (const float*)d_in[6];
  float* out = (float*)d_out;

  // workspace layout (needs ~302.3 MB)
  char* ws = (char*)d_ws;
  ushort_t* W1t   = (ushort_t*)(ws);                    // [E][H][D] bf16: 67108864 B
  ushort_t* W2t   = (ushort_t*)(ws + 67108864);         // [E][D][H] bf16: 67108864 B
  ushort_t* xg    = (ushort_t*)(ws + 134217728);        // [N][D]   bf16: 33554432 B
  ushort_t* hb    = (ushort_t*)(ws + 167772160);        // [N][H]   bf16: 134217728 B
  float*    rawbase = (float*)(ws + 301989888);         // [E][D] f32
  float*    adj   = (float*)(ws + 302022656);           // [E][D] f32
  int*      idx   = (int*)(ws + 302055424);             // [N]
  int*      perm  = (int*)(ws + 302120960);             // [N]
  int*      counts = (int*)(ws + 302186496);            // 8 + 8 cursor
  int*      cursor = counts + 8;
  int*      offsets = (int*)(ws + 302186624);           // 9 ints
  int*      meta   = (int*)(ws + 302186752);            // [n1, n2]
  int*      work1  = (int*)(ws + 302186880);            // <=2048 ints
  int*      work2  = (int*)(ws + 302195072);            // <=2048 ints

  init_kernel<<<32, 256, 0, stream>>>(counts, rawbase);
  transpose_bf16<<<dim3(H_ / 64, D_ / 64, E_), 256, 0, stream>>>(W1, W1t, D_, H_);
  transpose_bf16<<<dim3(D_ / 64, H_ / 64, E_), 256, 0, stream>>>(W2, W2t, H_, D_);
  base_kernel<<<dim3(4, E_, 8), 256, 0, stream>>>(b1, W2, rawbase);
  adj_kernel<<<32, 256, 0, stream>>>(rawbase, b2, adj);
  router_kernel<<<512, 256, 0, stream>>>(x, Wr, br, idx, counts);
  scan_build<<<1, 64, 0, stream>>>(counts, offsets, work1, work2, meta);
  scatter_kernel<<<NTOK / 4, 256, 0, stream>>>(x, idx, offsets, cursor, perm, xg);
  // worst-case tile counts: sum_e ceil(cnt_e/256) <= 71  ->  71*16=1136, 71*4=284
  ffn_gemm<1><<<1136, 512, 0, stream>>>(xg, W1t, b1, offsets, nullptr, nullptr, hb,
                                        work1, meta + 0);
  ffn_gemm<2><<<284, 512, 0, stream>>>(hb, W2t, adj, offsets, perm, out, nullptr,
                                       work2, meta + 1);
}